// Round 19
// baseline (430.186 us; speedup 1.0000x reference)
//
#include <hip/hip_runtime.h>

// LocalL1Loss: out = mean_{n,h,w} min_{7x7 shift} mean_c |in - shifted(tgt, zero-pad)|
// inputs/targets: (16, 3, 512, 512) fp32. Output: scalar fp32.
// R18: symmetric team pipeline. 8 waves = 2 teams x 4; step s: one team evals
// tile s (32x64) from buf[s&1], other team stages tile s+1 into buf[~s&1];
// roles swap by parity -> staging hides under eval, uniform code, no
// persistent role divergence (R14's spill trap). 512 blocks = 2/CU, single
// generation, 4 steps/block. Eval body = proven R4/R12 form.
// Model (R17 ablation): eval pipe-floor ~24us chip-wide; this targets the
// ~32us of serialized non-eval time.

constexpr int N = 16, C = 3, H = 512, W = 512;
constexpr int K = 7, HALO = 3;
constexpr int TH = 32, TW = 64;          // per-step output tile
constexpr int SM_ROWS = TH + 2 * HALO;   // 38
constexpr int SM_D = 36;                 // dwords/row: halves [w0-4 .. w0+67]
constexpr int BUF = C * SM_ROWS * SM_D;  // 4104 dwords
constexpr int BLK = 512;                 // 2 teams x 4 waves
constexpr int STEPS = 4;

typedef _Float16 h2 __attribute__((ext_vector_type(2)));
__device__ inline h2 u2h(unsigned u) { return __builtin_bit_cast(h2, u); }
__device__ inline h2 habs2(h2 x) {
    unsigned u = __builtin_bit_cast(unsigned, x) & 0x7fff7fffu;
    return __builtin_bit_cast(h2, u);
}
__device__ inline unsigned f2pk(float a, float b) {
    h2 v; v[0] = (_Float16)a; v[1] = (_Float16)b;
    return __builtin_bit_cast(unsigned, v);
}

// 256-thread staging of one 3x38x36-dword tile (p in [0,256))
__device__ __forceinline__ void stage_tile(const float* tbase, unsigned* buf,
                                           int h0, int w0, int p) {
    const bool interior = (h0 != 0) && (h0 != H - TH) && (w0 != 0) && (w0 != W - TW);
    int rr = p / SM_D;
    int d2 = p - rr * SM_D;
    int r  = rr;
    int c  = 0;
    const int f2base = w0 / 2 - 2;
    if (interior) {
        #pragma unroll
        for (int g = 0; g < 4; ++g) {     // 16 full iters as 4 batches of 4
            float2 v[4]; int idx[4];
            #pragma unroll
            for (int b = 0; b < 4; ++b) {
                const int gr = h0 + r - HALO;
                v[b] = reinterpret_cast<const float2*>(
                    tbase + ((size_t)c * H + gr) * W)[f2base + d2];
                idx[b] = rr * SM_D + d2;
                rr += 7; r += 7; d2 += 4;              // step 256 = 7*36 + 4
                if (d2 >= SM_D) { d2 -= SM_D; rr += 1; r += 1; }
                if (r >= SM_ROWS) { r -= SM_ROWS; c += 1; }
            }
            #pragma unroll
            for (int b = 0; b < 4; ++b)
                buf[idx[b]] = f2pk(v[b].x, v[b].y);
        }
        if (p < BUF - 16 * 256) {          // tail: 8 threads
            const int gr = h0 + r - HALO;
            float2 v2 = reinterpret_cast<const float2*>(
                tbase + ((size_t)c * H + gr) * W)[f2base + d2];
            buf[rr * SM_D + d2] = f2pk(v2.x, v2.y);
        }
    } else {
        #pragma unroll
        for (int it = 0; it < 17; ++it) {
            if (it < 16 || p < BUF - 16 * 256) {
                const int gr = h0 + r - HALO;
                const int gc = w0 - 4 + 2 * d2;
                float f0 = 0.0f, f1 = 0.0f;
                if ((unsigned)gr < (unsigned)H) {
                    const float* rowp = tbase + ((size_t)c * H + gr) * W;
                    if ((unsigned)gc       < (unsigned)W) f0 = rowp[gc];
                    if ((unsigned)(gc + 1) < (unsigned)W) f1 = rowp[gc + 1];
                }
                buf[rr * SM_D + d2] = f2pk(f0, f1);
            }
            rr += 7; r += 7; d2 += 4;
            if (d2 >= SM_D) { d2 -= SM_D; rr += 1; r += 1; }
            if (r >= SM_ROWS) { r -= SM_ROWS; c += 1; }
        }
    }
}

// eval one 32x64 tile (8 outputs/thread) against staged buffer
__device__ __forceinline__ float eval_tile(const unsigned* buf, const float* inputs,
                                           int n, int h, int wb, int ty, int tx) {
    const float* ibase = inputs + ((size_t)n * C * H + (size_t)h) * W + wb;
    float4 ia[3], ib[3];
    #pragma unroll
    for (int c = 0; c < 3; ++c) {
        ia[c] = *reinterpret_cast<const float4*>(ibase + (size_t)c * H * W);
        ib[c] = *reinterpret_cast<const float4*>(ibase + (size_t)c * H * W + 4);
    }
    h2 ipk[3][4];
    #pragma unroll
    for (int c = 0; c < 3; ++c) {
        ipk[c][0][0] = (_Float16)ia[c].x; ipk[c][0][1] = (_Float16)ia[c].y;
        ipk[c][1][0] = (_Float16)ia[c].z; ipk[c][1][1] = (_Float16)ia[c].w;
        ipk[c][2][0] = (_Float16)ib[c].x; ipk[c][2][1] = (_Float16)ib[c].y;
        ipk[c][3][0] = (_Float16)ib[c].z; ipk[c][3][1] = (_Float16)ib[c].w;
    }

    h2 bestA[4], bestB[4];
    #pragma unroll
    for (int p = 0; p < 4; ++p) { bestA[p] = u2h(0x7bff7bffu); bestB[p] = u2h(0x7bff7bffu); }

    #pragma unroll
    for (int di = 0; di < K; ++di) {
        unsigned t2[3][8];
        #pragma unroll
        for (int c = 0; c < 3; ++c) {
            const uint4* q = reinterpret_cast<const uint4*>(
                &buf[(c * SM_ROWS + (ty + di)) * SM_D + tx * 4]);
            uint4 lo = q[0], hi = q[1];
            t2[c][0] = lo.x; t2[c][1] = lo.y; t2[c][2] = lo.z; t2[c][3] = lo.w;
            t2[c][4] = hi.x; t2[c][5] = hi.y; t2[c][6] = hi.z; t2[c][7] = hi.w;
        }
        unsigned s[3][7];
        #pragma unroll
        for (int c = 0; c < 3; ++c)
            #pragma unroll
            for (int m = 0; m < 7; ++m)
                s[c][m] = __builtin_amdgcn_alignbit(t2[c][m + 1], t2[c][m], 16);

        #pragma unroll
        for (int dj = 0; dj < K; ++dj) {
            #pragma unroll
            for (int p = 0; p < 4; ++p) {
                h2 w0h, w1h, w2h;
                if (dj & 1) {
                    const int m = p + (dj + 1) / 2;
                    w0h = u2h(t2[0][m]); w1h = u2h(t2[1][m]); w2h = u2h(t2[2][m]);
                } else {
                    const int m = p + dj / 2;
                    w0h = u2h(s[0][m]); w1h = u2h(s[1][m]); w2h = u2h(s[2][m]);
                }
                h2 a0 = habs2(ipk[0][p] - w0h);
                h2 a1 = habs2(ipk[1][p] - w1h);
                h2 a2 = habs2(ipk[2][p] - w2h);
                h2 d  = a0 + a1 + a2;
                if (dj & 1) bestB[p] = __builtin_elementwise_min(bestB[p], d);
                else        bestA[p] = __builtin_elementwise_min(bestA[p], d);
            }
        }
    }

    float part = 0.0f;
    #pragma unroll
    for (int p = 0; p < 4; ++p) {
        h2 b = __builtin_elementwise_min(bestA[p], bestB[p]);
        part += (float)b[0] + (float)b[1];
    }
    return part;
}

__global__ __launch_bounds__(BLK, 4)
void local_l1_kernel(const float* __restrict__ inputs,
                     const float* __restrict__ targets,
                     float* __restrict__ out) {
    __shared__ unsigned sm_u[2 * BUF];   // 32,832 B -> 2 blocks/CU (grid-limited)

    const int tid = threadIdx.x;
    const int b   = blockIdx.x;
    // 2048 tiles = 16 n x 16 th x 8 tw; each block: 4 vertically-consecutive th
    const int n    = b >> 5;
    const int rem  = b & 31;
    const int tw   = rem >> 2;
    const int thq  = rem & 3;
    const int w0   = tw * 64;

    const float* tbase = targets + (size_t)n * C * H * W;
    const bool team0 = (tid < 256);
    const int lt = tid & 255;
    const int tx = lt & 7;
    const int ty = lt >> 3;
    const int wb = w0 + tx * 8;

    float part = 0.0f;

    // ---- prologue: team1 stages tile 0 into buf0 ----
    if (!team0) stage_tile(tbase, sm_u, (thq * 4) * TH, w0, lt);
    __syncthreads();

    // ---- 4 steps: parity decides roles ----
    #pragma unroll 1
    for (int s = 0; s < STEPS; ++s) {
        const bool my_eval = (team0 == ((s & 1) == 0));
        if (my_eval) {
            const int h0 = (thq * 4 + s) * TH;
            part += eval_tile(sm_u + (s & 1) * BUF, inputs, n, h0 + ty, wb, ty, tx);
        } else if (s + 1 < STEPS) {
            stage_tile(tbase, sm_u + ((s + 1) & 1) * BUF,
                       (thq * 4 + s + 1) * TH, w0, lt);
        }
        __syncthreads();
    }

    // ---- reduction ----
    #pragma unroll
    for (int off = 32; off > 0; off >>= 1)
        part += __shfl_down(part, off, 64);

    __shared__ float wsum[BLK / 64];
    if ((tid & 63) == 0) wsum[tid >> 6] = part;
    __syncthreads();
    if (tid == 0) {
        float total = 0.0f;
        #pragma unroll
        for (int i = 0; i < BLK / 64; ++i) total += wsum[i];
        atomicAdd(out, total * (1.0f / (3.0f * (float)N * (float)H * (float)W)));
    }
}

extern "C" void kernel_launch(void* const* d_in, const int* in_sizes, int n_in,
                              void* d_out, int out_size, void* d_ws, size_t ws_size,
                              hipStream_t stream) {
    const float* inputs  = (const float*)d_in[0];
    const float* targets = (const float*)d_in[1];
    float* out = (float*)d_out;

    (void)hipMemsetAsync(out, 0, sizeof(float), stream);
    local_l1_kernel<<<dim3(512), BLK, 0, stream>>>(inputs, targets, out);
}

// Round 20
// 55.343 us; speedup vs baseline: 7.7731x; 7.7731x over previous
//
#include <hip/hip_runtime.h>

// LocalL1Loss: out = mean_{n,h,w} min_{7x7 shift} mean_c |in - shifted(tgt, zero-pad)|
// inputs/targets: (16, 3, 512, 512) fp32. Output: scalar fp32.
// R19: fp32 end-to-end (R17 ablation => v_pk_f16 is ~half-rate; fp32 with
// abs-as-input-modifier + min3 folding beats it by ~35%, and kills all
// cvt/pack/alignbit ops). R12 staging/grid mechanics. LDS [3][70][76] floats,
// stride 76 -> 2 lanes/bank (free). Tripwire: WRITE_SIZE (spill).

constexpr int N = 16, C = 3, H = 512, W = 512;
constexpr int K = 7, HALO = 3;
constexpr int TH = 64, TW = 64;            // output tile per block
constexpr int SM_ROWS = TH + 2 * HALO;     // 70
constexpr int SM_COLS = 72;                // floats per row: w0-4 .. w0+67
constexpr int SM_STRIDE = 76;              // pad: 16B-aligned rows, 2-way banks
constexpr int BLK = 512;                   // 64 rows x 8 strips of 8 = 8 waves
constexpr int NP4 = C * SM_ROWS * 18;      // 3780 float4 staging positions

__global__ __launch_bounds__(BLK, 4)
void local_l1_kernel(const float* __restrict__ inputs,
                     const float* __restrict__ targets,
                     float* __restrict__ out) {
    __shared__ float sm_f[C * SM_ROWS * SM_STRIDE];   // 63,840 B -> 2 blocks/CU

    const int tid = threadIdx.x;
    const int w0 = blockIdx.x * TW;
    const int h0 = blockIdx.y * TH;
    const int n  = blockIdx.z;

    const int tx = tid & 7;     // strip index (w)
    const int ty = tid >> 3;    // row in tile (0..63)

    // ---- issue input loads FIRST so they overlap the staging burst ----
    const float* ibase = inputs + ((size_t)n * C * H + (size_t)(h0 + ty)) * W
                       + (w0 + tx * 8);
    float4 ia[3], ib[3];
    #pragma unroll
    for (int c = 0; c < 3; ++c) {
        ia[c] = *reinterpret_cast<const float4*>(ibase + (size_t)c * H * W);
        ib[c] = *reinterpret_cast<const float4*>(ibase + (size_t)c * H * W + 4);
    }

    // ---- stage targets tile into LDS as fp32 (pure copy, batched) ----
    // position p = c*(70*18) + r*18 + d4 ; LDS idx (c*70+r)*76 + 4*d4 ;
    // global: row h0-3+r, col w0-4+4*d4. Step 512 = 28*18 + 8.
    const float* tbase = targets + (size_t)n * C * H * W;
    const bool interior = (h0 != 0) && (h0 != H - TH) && (w0 != 0) && (w0 != W - TW);
    {
        int r  = tid / 18;
        int d4 = tid - r * 18;
        int c  = 0;
        if (interior) {
            float4 v[4]; int idx[4];
            #pragma unroll
            for (int b = 0; b < 4; ++b) {              // iters 0..3
                v[b] = *reinterpret_cast<const float4*>(
                    tbase + ((size_t)c * H + (h0 - HALO + r)) * W + (w0 - 4 + 4 * d4));
                idx[b] = (c * SM_ROWS + r) * SM_STRIDE + 4 * d4;
                r += 28; d4 += 8;
                if (d4 >= 18) { d4 -= 18; r += 1; }
                if (r >= SM_ROWS) { r -= SM_ROWS; c += 1; }
            }
            #pragma unroll
            for (int b = 0; b < 4; ++b)
                *reinterpret_cast<float4*>(&sm_f[idx[b]]) = v[b];
            #pragma unroll
            for (int b = 0; b < 3; ++b) {              // iters 4..6
                v[b] = *reinterpret_cast<const float4*>(
                    tbase + ((size_t)c * H + (h0 - HALO + r)) * W + (w0 - 4 + 4 * d4));
                idx[b] = (c * SM_ROWS + r) * SM_STRIDE + 4 * d4;
                r += 28; d4 += 8;
                if (d4 >= 18) { d4 -= 18; r += 1; }
                if (r >= SM_ROWS) { r -= SM_ROWS; c += 1; }
            }
            #pragma unroll
            for (int b = 0; b < 3; ++b)
                *reinterpret_cast<float4*>(&sm_f[idx[b]]) = v[b];
            if (tid < NP4 - 7 * BLK) {                 // tail: 196 threads
                float4 vv = *reinterpret_cast<const float4*>(
                    tbase + ((size_t)c * H + (h0 - HALO + r)) * W + (w0 - 4 + 4 * d4));
                *reinterpret_cast<float4*>(&sm_f[(c * SM_ROWS + r) * SM_STRIDE + 4 * d4]) = vv;
            }
        } else {
            #pragma unroll
            for (int it = 0; it < 8; ++it) {
                if (it < 7 || tid < NP4 - 7 * BLK) {
                    const int gr = h0 - HALO + r;
                    const int gc = w0 - 4 + 4 * d4;
                    const bool ok = ((unsigned)gr < (unsigned)H) && (gc >= 0) && (gc + 4 <= W);
                    const int grc = gr < 0 ? 0 : (gr > H - 1 ? H - 1 : gr);
                    const int gcc = gc < 0 ? 0 : (gc > W - 4 ? W - 4 : gc);
                    float4 vv = *reinterpret_cast<const float4*>(
                        tbase + ((size_t)c * H + grc) * W + gcc);
                    if (!ok) { vv.x = 0.f; vv.y = 0.f; vv.z = 0.f; vv.w = 0.f; }
                    *reinterpret_cast<float4*>(&sm_f[(c * SM_ROWS + r) * SM_STRIDE + 4 * d4]) = vv;
                }
                r += 28; d4 += 8;
                if (d4 >= 18) { d4 -= 18; r += 1; }
                if (r >= SM_ROWS) { r -= SM_ROWS; c += 1; }
            }
        }
    }

    float in[3][8];
    #pragma unroll
    for (int c = 0; c < 3; ++c) {
        in[c][0] = ia[c].x; in[c][1] = ia[c].y; in[c][2] = ia[c].z; in[c][3] = ia[c].w;
        in[c][4] = ib[c].x; in[c][5] = ib[c].y; in[c][6] = ib[c].z; in[c][7] = ib[c].w;
    }
    __syncthreads();

    // ---- main loop: 8 outputs/thread, fp32, min3-folded shifts ----
    float best[8];
    #pragma unroll
    for (int o = 0; o < 8; ++o) best[o] = 3.0e38f;

    #pragma unroll
    for (int di = 0; di < K; ++di) {
        // 16 floats per channel: cols (w0-4+8tx) .. +15  => fr[k] = col wb-4+k
        float fr[3][16];
        #pragma unroll
        for (int c = 0; c < 3; ++c) {
            const float* rp = &sm_f[(c * SM_ROWS + (ty + di)) * SM_STRIDE + 8 * tx];
            #pragma unroll
            for (int j = 0; j < 4; ++j) {
                float4 v = *reinterpret_cast<const float4*>(rp + 4 * j);
                fr[c][4 * j]     = v.x; fr[c][4 * j + 1] = v.y;
                fr[c][4 * j + 2] = v.z; fr[c][4 * j + 3] = v.w;
            }
        }
        // output o, shift dj: target fr[o + dj + 1]
        #pragma unroll
        for (int o = 0; o < 8; ++o) {
            float d0 = fabsf(in[0][o] - fr[0][o + 1])
                     + fabsf(in[1][o] - fr[1][o + 1])
                     + fabsf(in[2][o] - fr[2][o + 1]);
            float d1 = fabsf(in[0][o] - fr[0][o + 2])
                     + fabsf(in[1][o] - fr[1][o + 2])
                     + fabsf(in[2][o] - fr[2][o + 2]);
            best[o] = fminf(fminf(best[o], d0), d1);
            float d2 = fabsf(in[0][o] - fr[0][o + 3])
                     + fabsf(in[1][o] - fr[1][o + 3])
                     + fabsf(in[2][o] - fr[2][o + 3]);
            float d3 = fabsf(in[0][o] - fr[0][o + 4])
                     + fabsf(in[1][o] - fr[1][o + 4])
                     + fabsf(in[2][o] - fr[2][o + 4]);
            best[o] = fminf(fminf(best[o], d2), d3);
            float d4 = fabsf(in[0][o] - fr[0][o + 5])
                     + fabsf(in[1][o] - fr[1][o + 5])
                     + fabsf(in[2][o] - fr[2][o + 5]);
            float d5 = fabsf(in[0][o] - fr[0][o + 6])
                     + fabsf(in[1][o] - fr[1][o + 6])
                     + fabsf(in[2][o] - fr[2][o + 6]);
            best[o] = fminf(fminf(best[o], d4), d5);
            float d6 = fabsf(in[0][o] - fr[0][o + 7])
                     + fabsf(in[1][o] - fr[1][o + 7])
                     + fabsf(in[2][o] - fr[2][o + 7]);
            best[o] = fminf(best[o], d6);
        }
    }

    float part = 0.0f;
    #pragma unroll
    for (int o = 0; o < 8; ++o) part += best[o];

    // wave (64-lane) reduction, then cross-wave via LDS
    #pragma unroll
    for (int off = 32; off > 0; off >>= 1)
        part += __shfl_down(part, off, 64);

    __shared__ float wsum[BLK / 64];
    if ((tid & 63) == 0) wsum[tid >> 6] = part;
    __syncthreads();
    if (tid == 0) {
        float total = 0.0f;
        #pragma unroll
        for (int i = 0; i < BLK / 64; ++i) total += wsum[i];
        atomicAdd(out, total * (1.0f / (3.0f * (float)N * (float)H * (float)W)));
    }
}

extern "C" void kernel_launch(void* const* d_in, const int* in_sizes, int n_in,
                              void* d_out, int out_size, void* d_ws, size_t ws_size,
                              hipStream_t stream) {
    const float* inputs  = (const float*)d_in[0];
    const float* targets = (const float*)d_in[1];
    float* out = (float*)d_out;

    (void)hipMemsetAsync(out, 0, sizeof(float), stream);
    dim3 grid(W / TW, H / TH, N);
    local_l1_kernel<<<grid, BLK, 0, stream>>>(inputs, targets, out);
}

// Round 21
// 48.646 us; speedup vs baseline: 8.8431x; 1.1377x over previous
//
#include <hip/hip_runtime.h>

// LocalL1Loss: out = mean_{n,h,w} min_{7x7 shift} mean_c |in - shifted(tgt, zero-pad)|
// inputs/targets: (16, 3, 512, 512) fp32. Output: scalar fp32.
// R20: R19 (fp32, best 55.3us) + strip-offset swizzle col'=col+4*(col>>5),
// row stride 80. R19's eval b128 groups had tx/tx+4 bank collisions (2x per
// read, 14.6M conflicts ~ 24us LDS serialization). Swizzled strip starts
// {0,8,16,24,4,12,20,28} are conflict-free per 8-lane group. Eval reads
// own-strip + neighbor-strip, reassembled linearly in regs.

constexpr int N = 16, C = 3, H = 512, W = 512;
constexpr int K = 7, HALO = 3;
constexpr int TH = 64, TW = 64;            // output tile per block
constexpr int SM_ROWS = TH + 2 * HALO;     // 70
constexpr int SM_STRIDE = 80;              // swizzled row stride (72 data + 8)
constexpr int BLK = 512;                   // 64 rows x 8 strips of 8 = 8 waves
constexpr int NP4 = C * SM_ROWS * 18;      // 3780 float4 staging positions

__device__ inline int colp(int col) { return col + 4 * (col >> 5); }

__global__ __launch_bounds__(BLK, 4)
void local_l1_kernel(const float* __restrict__ inputs,
                     const float* __restrict__ targets,
                     float* __restrict__ out) {
    __shared__ float sm_f[C * SM_ROWS * SM_STRIDE];   // 67,200 B -> 2 blocks/CU

    const int tid = threadIdx.x;
    const int w0 = blockIdx.x * TW;
    const int h0 = blockIdx.y * TH;
    const int n  = blockIdx.z;

    const int tx = tid & 7;     // strip index (w)
    const int ty = tid >> 3;    // row in tile (0..63)

    // ---- issue input loads FIRST so they overlap the staging burst ----
    const float* ibase = inputs + ((size_t)n * C * H + (size_t)(h0 + ty)) * W
                       + (w0 + tx * 8);
    float4 ia[3], ib[3];
    #pragma unroll
    for (int c = 0; c < 3; ++c) {
        ia[c] = *reinterpret_cast<const float4*>(ibase + (size_t)c * H * W);
        ib[c] = *reinterpret_cast<const float4*>(ibase + (size_t)c * H * W + 4);
    }

    // ---- stage targets tile into LDS as fp32, swizzled layout ----
    // position p = c*(70*18) + r*18 + d4 ; LDS idx (c*70+r)*80 + colp(4*d4) ;
    // global: row h0-3+r, col w0-4+4*d4. Step 512 = 28*18 + 8.
    const float* tbase = targets + (size_t)n * C * H * W;
    const bool interior = (h0 != 0) && (h0 != H - TH) && (w0 != 0) && (w0 != W - TW);
    {
        int r  = tid / 18;
        int d4 = tid - r * 18;
        int c  = 0;
        if (interior) {
            float4 v[4]; int idx[4];
            #pragma unroll
            for (int b = 0; b < 4; ++b) {              // iters 0..3
                v[b] = *reinterpret_cast<const float4*>(
                    tbase + ((size_t)c * H + (h0 - HALO + r)) * W + (w0 - 4 + 4 * d4));
                idx[b] = (c * SM_ROWS + r) * SM_STRIDE + colp(4 * d4);
                r += 28; d4 += 8;
                if (d4 >= 18) { d4 -= 18; r += 1; }
                if (r >= SM_ROWS) { r -= SM_ROWS; c += 1; }
            }
            #pragma unroll
            for (int b = 0; b < 4; ++b)
                *reinterpret_cast<float4*>(&sm_f[idx[b]]) = v[b];
            #pragma unroll
            for (int b = 0; b < 3; ++b) {              // iters 4..6
                v[b] = *reinterpret_cast<const float4*>(
                    tbase + ((size_t)c * H + (h0 - HALO + r)) * W + (w0 - 4 + 4 * d4));
                idx[b] = (c * SM_ROWS + r) * SM_STRIDE + colp(4 * d4);
                r += 28; d4 += 8;
                if (d4 >= 18) { d4 -= 18; r += 1; }
                if (r >= SM_ROWS) { r -= SM_ROWS; c += 1; }
            }
            #pragma unroll
            for (int b = 0; b < 3; ++b)
                *reinterpret_cast<float4*>(&sm_f[idx[b]]) = v[b];
            if (tid < NP4 - 7 * BLK) {                 // tail: 196 threads
                float4 vv = *reinterpret_cast<const float4*>(
                    tbase + ((size_t)c * H + (h0 - HALO + r)) * W + (w0 - 4 + 4 * d4));
                *reinterpret_cast<float4*>(
                    &sm_f[(c * SM_ROWS + r) * SM_STRIDE + colp(4 * d4)]) = vv;
            }
        } else {
            #pragma unroll
            for (int it = 0; it < 8; ++it) {
                if (it < 7 || tid < NP4 - 7 * BLK) {
                    const int gr = h0 - HALO + r;
                    const int gc = w0 - 4 + 4 * d4;
                    const bool ok = ((unsigned)gr < (unsigned)H) && (gc >= 0) && (gc + 4 <= W);
                    const int grc = gr < 0 ? 0 : (gr > H - 1 ? H - 1 : gr);
                    const int gcc = gc < 0 ? 0 : (gc > W - 4 ? W - 4 : gc);
                    float4 vv = *reinterpret_cast<const float4*>(
                        tbase + ((size_t)c * H + grc) * W + gcc);
                    if (!ok) { vv.x = 0.f; vv.y = 0.f; vv.z = 0.f; vv.w = 0.f; }
                    *reinterpret_cast<float4*>(
                        &sm_f[(c * SM_ROWS + r) * SM_STRIDE + colp(4 * d4)]) = vv;
                }
                r += 28; d4 += 8;
                if (d4 >= 18) { d4 -= 18; r += 1; }
                if (r >= SM_ROWS) { r -= SM_ROWS; c += 1; }
            }
        }
    }

    float in[3][8];
    #pragma unroll
    for (int c = 0; c < 3; ++c) {
        in[c][0] = ia[c].x; in[c][1] = ia[c].y; in[c][2] = ia[c].z; in[c][3] = ia[c].w;
        in[c][4] = ib[c].x; in[c][5] = ib[c].y; in[c][6] = ib[c].z; in[c][7] = ib[c].w;
    }
    __syncthreads();

    // ---- main loop: 8 outputs/thread, fp32, min3-folded shifts ----
    float best[8];
    #pragma unroll
    for (int o = 0; o < 8; ++o) best[o] = 3.0e38f;

    const int own_off = colp(8 * tx);          // own strip (cols 8tx..8tx+7)
    const int nb_off  = colp(8 * (tx + 1));    // neighbor strip (next 8 cols)

    #pragma unroll
    for (int di = 0; di < K; ++di) {
        // 16 floats per channel: LDS cols 8tx..8tx+15 (global w0-4+8tx ..)
        float fr[3][16];
        #pragma unroll
        for (int c = 0; c < 3; ++c) {
            const float* rowp = &sm_f[(c * SM_ROWS + (ty + di)) * SM_STRIDE];
            float4 v0 = *reinterpret_cast<const float4*>(rowp + own_off);
            float4 v1 = *reinterpret_cast<const float4*>(rowp + own_off + 4);
            float4 v2 = *reinterpret_cast<const float4*>(rowp + nb_off);
            float4 v3 = *reinterpret_cast<const float4*>(rowp + nb_off + 4);
            fr[c][0]  = v0.x; fr[c][1]  = v0.y; fr[c][2]  = v0.z; fr[c][3]  = v0.w;
            fr[c][4]  = v1.x; fr[c][5]  = v1.y; fr[c][6]  = v1.z; fr[c][7]  = v1.w;
            fr[c][8]  = v2.x; fr[c][9]  = v2.y; fr[c][10] = v2.z; fr[c][11] = v2.w;
            fr[c][12] = v3.x; fr[c][13] = v3.y; fr[c][14] = v3.z; fr[c][15] = v3.w;
        }
        // output o, shift dj: target fr[o + dj + 1]
        #pragma unroll
        for (int o = 0; o < 8; ++o) {
            float d0 = fabsf(in[0][o] - fr[0][o + 1])
                     + fabsf(in[1][o] - fr[1][o + 1])
                     + fabsf(in[2][o] - fr[2][o + 1]);
            float d1 = fabsf(in[0][o] - fr[0][o + 2])
                     + fabsf(in[1][o] - fr[1][o + 2])
                     + fabsf(in[2][o] - fr[2][o + 2]);
            best[o] = fminf(fminf(best[o], d0), d1);
            float d2 = fabsf(in[0][o] - fr[0][o + 3])
                     + fabsf(in[1][o] - fr[1][o + 3])
                     + fabsf(in[2][o] - fr[2][o + 3]);
            float d3 = fabsf(in[0][o] - fr[0][o + 4])
                     + fabsf(in[1][o] - fr[1][o + 4])
                     + fabsf(in[2][o] - fr[2][o + 4]);
            best[o] = fminf(fminf(best[o], d2), d3);
            float d4 = fabsf(in[0][o] - fr[0][o + 5])
                     + fabsf(in[1][o] - fr[1][o + 5])
                     + fabsf(in[2][o] - fr[2][o + 5]);
            float d5 = fabsf(in[0][o] - fr[0][o + 6])
                     + fabsf(in[1][o] - fr[1][o + 6])
                     + fabsf(in[2][o] - fr[2][o + 6]);
            best[o] = fminf(fminf(best[o], d4), d5);
            float d6 = fabsf(in[0][o] - fr[0][o + 7])
                     + fabsf(in[1][o] - fr[1][o + 7])
                     + fabsf(in[2][o] - fr[2][o + 7]);
            best[o] = fminf(best[o], d6);
        }
    }

    float part = 0.0f;
    #pragma unroll
    for (int o = 0; o < 8; ++o) part += best[o];

    // wave (64-lane) reduction, then cross-wave via LDS
    #pragma unroll
    for (int off = 32; off > 0; off >>= 1)
        part += __shfl_down(part, off, 64);

    __shared__ float wsum[BLK / 64];
    if ((tid & 63) == 0) wsum[tid >> 6] = part;
    __syncthreads();
    if (tid == 0) {
        float total = 0.0f;
        #pragma unroll
        for (int i = 0; i < BLK / 64; ++i) total += wsum[i];
        atomicAdd(out, total * (1.0f / (3.0f * (float)N * (float)H * (float)W)));
    }
}

extern "C" void kernel_launch(void* const* d_in, const int* in_sizes, int n_in,
                              void* d_out, int out_size, void* d_ws, size_t ws_size,
                              hipStream_t stream) {
    const float* inputs  = (const float*)d_in[0];
    const float* targets = (const float*)d_in[1];
    float* out = (float*)d_out;

    (void)hipMemsetAsync(out, 0, sizeof(float), stream);
    dim3 grid(W / TW, H / TH, N);
    local_l1_kernel<<<grid, BLK, 0, stream>>>(inputs, targets, out);
}